// Round 3
// baseline (167.399 us; speedup 1.0000x reference)
//
#include <hip/hip_runtime.h>

// Conv2D 15x15 valid, 4096^2 fp32 -> 4082^2 fp32, via bf16 MFMA Toeplitz-band.
//
// R3: R1 frame (16x16x32 MFMA, 64x64 tile, 256 thr, B-table in d_ws, L1-hot
// in-loop B loads) + DPP row-rotation of A-fragments across the kh loop.
//
// Key identity: A-frag(kh+1, t) for lane m == A-frag(kh, t) of lane m+1
// (rows slide down by one per kh). m-groups (lane&15) are DPP rows, so
// v_mov_b32_dpp row_shl:1 (lane i <- lane i+1) replaces a 1 KB ds_read_b128;
// only lanes m==15 refresh from LDS (exec-masked b128, 64 B/wave). LDS read
// traffic: 240 KB/block -> ~20 KB/block (-94%); work shifts to VALU (15% busy).
//
// R2 post-mortem (62 us, reverted): 32x32x16 killed bank conflicts (4.17M ->
// 217K) but time ROSE -> conflicts were not binding. Its 45 KB B-table missed
// L1 (737 MB L2 traffic) and did 1.5x the MFMA FLOPs. B must stay L1/register
// resident; 15 KB table of the 16x16x32 form fits L1.

#define HIN 4096
#define WIN 4096
#define KH 15
#define KW 15
#define OH (HIN - KH + 1)  // 4082
#define OW (WIN - KW + 1)  // 4082

#define BX 64
#define BY 64
#define XROWS (BY + KH - 1)     // 78 staged input rows
#define XCOLS 80                // staged input cols (64 + 14, padded to 80)
#define LDSW 88                 // bf16 row stride (176 B -> bank skew 12 dwords)
#define NSH (XROWS * LDSW)      // 6864 shorts = 13728 B LDS
#define NB4 (XCOLS / 4)         // 20 float4 per staged row
#define NITEM (XROWS * NB4)     // 1560 staging items per block

typedef short bf16x8 __attribute__((ext_vector_type(8)));
typedef int   i32x4  __attribute__((ext_vector_type(4)));
typedef float f32x4  __attribute__((ext_vector_type(4)));

static __device__ inline short f2bf(float f) {  // fp32 -> bf16 RNE
    unsigned u = __float_as_uint(f);
    u += 0x7fffu + ((u >> 16) & 1u);
    return (short)(u >> 16);
}

// DPP row_shl:1 (ctrl 0x101): within each 16-lane row, lane i <- lane i+1.
// Row-boundary lanes (m==15) get old=0; caller overwrites them from LDS.
static __device__ inline bf16x8 rot_up(bf16x8 f) {
    i32x4 fi = __builtin_bit_cast(i32x4, f);
#pragma unroll
    for (int d = 0; d < 4; ++d)
        fi[d] = __builtin_amdgcn_update_dpp(0, fi[d], 0x101, 0xf, 0xf, false);
    return __builtin_bit_cast(bf16x8, fi);
}

// ---- prep: build B-fragment table (15 kh x 64 lanes x bf16x8) once in ws ----
// 16x16x32 B-operand layout: lane L holds B[k=(L>>4)*8+j][n=L&15], j=0..7,
// with B[k][n] = w[kh][k-n] (0 outside band).
__global__ void conv2d_btab(const float* __restrict__ w, short* __restrict__ btab) {
    const int e = blockIdx.x * 256 + threadIdx.x;
    if (e >= KH * 64) return;
    const int kh = e >> 6;
    const int L  = e & 63;
    const int n  = L & 15;
    const int q  = L >> 4;
    bf16x8 bv;
#pragma unroll
    for (int j = 0; j < 8; ++j) {
        const int d = q * 8 + j - n;          // k - n
        bv[j] = (d >= 0 && d < KW) ? f2bf(w[kh * KW + d]) : (short)0;
    }
    *reinterpret_cast<bf16x8*>(&btab[(size_t)e * 8]) = bv;
}

__global__ __launch_bounds__(256, 8)
void conv2d_mfma(const float* __restrict__ x,
                 const short* __restrict__ btab,
                 const float* __restrict__ bias,
                 float* __restrict__ out) {
    __shared__ short lds[NSH];

    const int tid = threadIdx.x;
    const int ox0 = blockIdx.x * BX;
    const int oy0 = blockIdx.y * BY;

    // ---------------- stage x tile: 78 x 80 fp32 -> bf16 LDS ----------------
    if (ox0 + XCOLS <= WIN && oy0 + XROWS <= HIN) {
        // interior fast path: no clamps; batch-issue all loads, then convert
        float4 v[7];
#pragma unroll
        for (int i = 0; i < 7; ++i) {
            const int f = tid + 256 * i;
            if (f < NITEM) {
                const int r  = f / NB4;
                const int c4 = (f - r * NB4) * 4;
                v[i] = *reinterpret_cast<const float4*>(&x[(size_t)(oy0 + r) * WIN + ox0 + c4]);
            }
        }
#pragma unroll
        for (int i = 0; i < 7; ++i) {
            const int f = tid + 256 * i;
            if (f < NITEM) {
                const int r  = f / NB4;
                const int c4 = (f - r * NB4) * 4;
                short4 s;
                s.x = f2bf(v[i].x); s.y = f2bf(v[i].y);
                s.z = f2bf(v[i].z); s.w = f2bf(v[i].w);
                *reinterpret_cast<short4*>(&lds[r * LDSW + c4]) = s;   // ds_write_b64
            }
        }
    } else {
        // edge blocks (bx==63 or by==63): clamped per-item path
        for (int f = tid; f < NITEM; f += 256) {
            const int r  = f / NB4;
            const int c4 = (f - r * NB4) * 4;
            int gy = oy0 + r;
            if (gy > HIN - 1) gy = HIN - 1;   // clamped rows feed only masked outputs
            const int gx = ox0 + c4;
            float4 v;
            if (gx + 3 <= WIN - 1) {
                v = *reinterpret_cast<const float4*>(&x[(size_t)gy * WIN + gx]);
            } else {
                const float* row = &x[(size_t)gy * WIN];
                const int x0 = (gx + 0 > WIN - 1) ? WIN - 1 : gx + 0;
                const int x1 = (gx + 1 > WIN - 1) ? WIN - 1 : gx + 1;
                const int x2 = (gx + 2 > WIN - 1) ? WIN - 1 : gx + 2;
                const int x3 = (gx + 3 > WIN - 1) ? WIN - 1 : gx + 3;
                v = make_float4(row[x0], row[x1], row[x2], row[x3]);
            }
            short4 s;
            s.x = f2bf(v.x); s.y = f2bf(v.y); s.z = f2bf(v.z); s.w = f2bf(v.w);
            *reinterpret_cast<short4*>(&lds[r * LDSW + c4]) = s;
        }
    }
    __syncthreads();

    // ---------------- compute: 15 kh x 4 x-tiles of 16x16 MFMA ----------------
    const int lane = tid & 63;
    const int wv   = tid >> 6;        // wave id 0..3 -> output rows [16*wv, +16)
    const int m    = lane & 15;       // A-row (and D-col) index
    const int q    = lane >> 4;       // quad

    f32x4 acc[4];
#pragma unroll
    for (int t = 0; t < 4; ++t) acc[t] = (f32x4){0.f, 0.f, 0.f, 0.f};

    // A-frag base: row (16*wv + m), col q*8 + t*16 (imm-friendly offsets)
    const short*  abase = &lds[(wv * 16 + m) * LDSW + q * 8];
    const bf16x8* bt    = reinterpret_cast<const bf16x8*>(btab) + lane;

    // initial fragments (kh = 0): one full ds_read_b128 per t
    bf16x8 frag0, frag1, frag2, frag3;
    frag0 = *reinterpret_cast<const bf16x8*>(abase + 0 * 16);
    frag1 = *reinterpret_cast<const bf16x8*>(abase + 1 * 16);
    frag2 = *reinterpret_cast<const bf16x8*>(abase + 2 * 16);
    frag3 = *reinterpret_cast<const bf16x8*>(abase + 3 * 16);

#pragma unroll
    for (int kh = 0; kh < KH; ++kh) {
        if (kh) {
            // slide the A window down one row: lane m takes lane m+1's frag
            frag0 = rot_up(frag0);
            frag1 = rot_up(frag1);
            frag2 = rot_up(frag2);
            frag3 = rot_up(frag3);
            if (m == 15) {   // boundary lanes fetch the newly-exposed row
                frag0 = *reinterpret_cast<const bf16x8*>(abase + kh * LDSW + 0 * 16);
                frag1 = *reinterpret_cast<const bf16x8*>(abase + kh * LDSW + 1 * 16);
                frag2 = *reinterpret_cast<const bf16x8*>(abase + kh * LDSW + 2 * 16);
                frag3 = *reinterpret_cast<const bf16x8*>(abase + kh * LDSW + 3 * 16);
            }
        }
        const bf16x8 b = bt[kh * 64];   // global dwordx4, L1-hot (15 KB table)
        acc[0] = __builtin_amdgcn_mfma_f32_16x16x32_bf16(frag0, b, acc[0], 0, 0, 0);
        acc[1] = __builtin_amdgcn_mfma_f32_16x16x32_bf16(frag1, b, acc[1], 0, 0, 0);
        acc[2] = __builtin_amdgcn_mfma_f32_16x16x32_bf16(frag2, b, acc[2], 0, 0, 0);
        acc[3] = __builtin_amdgcn_mfma_f32_16x16x32_bf16(frag3, b, acc[3], 0, 0, 0);
    }

    // ---------------- epilogue: D layout col=lane&15, row=q*4+reg ----------------
    const float b0 = bias[0];
    const int row0 = oy0 + wv * 16 + q * 4;
#pragma unroll
    for (int t = 0; t < 4; ++t) {
        const int col = ox0 + t * 16 + m;
        if (col < OW) {
            const f32x4 a = (t == 0) ? acc[0] : (t == 1) ? acc[1] : (t == 2) ? acc[2] : acc[3];
#pragma unroll
            for (int r = 0; r < 4; ++r) {
                const int row = row0 + r;
                if (row < OH)
                    out[(size_t)row * OW + col] = a[r] + b0;
            }
        }
    }
}

extern "C" void kernel_launch(void* const* d_in, const int* in_sizes, int n_in,
                              void* d_out, int out_size, void* d_ws, size_t ws_size,
                              hipStream_t stream) {
    const float* x    = (const float*)d_in[0];
    const float* w    = (const float*)d_in[1];
    const float* bias = (const float*)d_in[2];
    float* out        = (float*)d_out;
    short* btab       = (short*)d_ws;   // 15*64*8 shorts = 15360 B

    conv2d_btab<<<dim3((KH * 64 + 255) / 256), dim3(256), 0, stream>>>(w, btab);

    dim3 grid((OW + BX - 1) / BX, (OH + BY - 1) / BY);  // 64 x 64
    dim3 block(256);
    conv2d_mfma<<<grid, block, 0, stream>>>(x, btab, bias, out);
}

// Round 4
// 136.525 us; speedup vs baseline: 1.2261x; 1.2261x over previous
//
#include <hip/hip_runtime.h>

// Conv2D 15x15 valid, 4096^2 fp32 -> 4082^2 fp32, via bf16 MFMA Toeplitz-band.
//
// R4: R1 frame (16x16x32 MFMA, 64x64 tile, 256 thr, prep-kernel B-table in
// d_ws) + B[15] hoisted into 60 VGPRs once per block (15 coalesced dwordx4,
// L2-hot). Removes 240 in-loop vector-mem loads/block (~60k cy/CU on the TA
// pipe + ~200cy latency on every MFMA's B operand) that R1 paid.
// __launch_bounds__(256,4): 128-VGPR cap fits 60 B-regs + 16 acc AGPRs with
// no spill (R3 post-mortem: the (256,8) 64-VGPR cap forced a 67 MB scratch
// spill, visible as WRITE_SIZE 71.5->138 MB).
//
// History: R1 50us (B in-loop from L1); R2 62us (32x32, B streamed L2 - bad);
// R3 80us (DPP rotation -> spill). In-loop kh: only ds_read_b128 A-stream,
// compiler pipelines vs MFMA with counted lgkmcnt.

#define HIN 4096
#define WIN 4096
#define KH 15
#define KW 15
#define OH (HIN - KH + 1)  // 4082
#define OW (WIN - KW + 1)  // 4082

#define BX 64
#define BY 64
#define XROWS (BY + KH - 1)     // 78 staged input rows
#define XCOLS 80                // staged input cols (64 + 14, padded to 80)
#define LDSW 88                 // bf16 row stride (176 B -> bank skew 12 dwords)
#define NSH (XROWS * LDSW)      // 6864 shorts = 13728 B LDS
#define NB4 (XCOLS / 4)         // 20 float4 per staged row
#define NITEM (XROWS * NB4)     // 1560 staging items per block

typedef short bf16x8 __attribute__((ext_vector_type(8)));
typedef float f32x4  __attribute__((ext_vector_type(4)));

static __device__ inline short f2bf(float f) {  // fp32 -> bf16 RNE
    unsigned u = __float_as_uint(f);
    u += 0x7fffu + ((u >> 16) & 1u);
    return (short)(u >> 16);
}

// ---- prep: build B-fragment table (15 kh x 64 lanes x bf16x8) once in ws ----
// 16x16x32 B-operand layout: lane L holds B[k=(L>>4)*8+j][n=L&15], j=0..7,
// with B[k][n] = w[kh][k-n] (0 outside band).
__global__ void conv2d_btab(const float* __restrict__ w, short* __restrict__ btab) {
    const int e = blockIdx.x * 256 + threadIdx.x;
    if (e >= KH * 64) return;
    const int kh = e >> 6;
    const int L  = e & 63;
    const int n  = L & 15;
    const int q  = L >> 4;
    bf16x8 bv;
#pragma unroll
    for (int j = 0; j < 8; ++j) {
        const int d = q * 8 + j - n;          // k - n
        bv[j] = (d >= 0 && d < KW) ? f2bf(w[kh * KW + d]) : (short)0;
    }
    *reinterpret_cast<bf16x8*>(&btab[(size_t)e * 8]) = bv;
}

__global__ __launch_bounds__(256, 4)
void conv2d_mfma(const float* __restrict__ x,
                 const short* __restrict__ btab,
                 const float* __restrict__ bias,
                 float* __restrict__ out) {
    __shared__ short lds[NSH];

    const int tid = threadIdx.x;
    const int ox0 = blockIdx.x * BX;
    const int oy0 = blockIdx.y * BY;

    // ---------------- stage x tile: 78 x 80 fp32 -> bf16 LDS ----------------
    if (ox0 + XCOLS <= WIN && oy0 + XROWS <= HIN) {
        // interior fast path: no clamps; batch-issue all loads, then convert
        float4 v[7];
#pragma unroll
        for (int i = 0; i < 7; ++i) {
            const int f = tid + 256 * i;
            if (f < NITEM) {
                const int r  = f / NB4;
                const int c4 = (f - r * NB4) * 4;
                v[i] = *reinterpret_cast<const float4*>(&x[(size_t)(oy0 + r) * WIN + ox0 + c4]);
            }
        }
#pragma unroll
        for (int i = 0; i < 7; ++i) {
            const int f = tid + 256 * i;
            if (f < NITEM) {
                const int r  = f / NB4;
                const int c4 = (f - r * NB4) * 4;
                short4 s;
                s.x = f2bf(v[i].x); s.y = f2bf(v[i].y);
                s.z = f2bf(v[i].z); s.w = f2bf(v[i].w);
                *reinterpret_cast<short4*>(&lds[r * LDSW + c4]) = s;   // ds_write_b64
            }
        }
    } else {
        // edge blocks (bx==63 or by==63): clamped per-item path
        for (int f = tid; f < NITEM; f += 256) {
            const int r  = f / NB4;
            const int c4 = (f - r * NB4) * 4;
            int gy = oy0 + r;
            if (gy > HIN - 1) gy = HIN - 1;   // clamped rows feed only masked outputs
            const int gx = ox0 + c4;
            float4 v;
            if (gx + 3 <= WIN - 1) {
                v = *reinterpret_cast<const float4*>(&x[(size_t)gy * WIN + gx]);
            } else {
                const float* row = &x[(size_t)gy * WIN];
                const int x0 = (gx + 0 > WIN - 1) ? WIN - 1 : gx + 0;
                const int x1 = (gx + 1 > WIN - 1) ? WIN - 1 : gx + 1;
                const int x2 = (gx + 2 > WIN - 1) ? WIN - 1 : gx + 2;
                const int x3 = (gx + 3 > WIN - 1) ? WIN - 1 : gx + 3;
                v = make_float4(row[x0], row[x1], row[x2], row[x3]);
            }
            short4 s;
            s.x = f2bf(v.x); s.y = f2bf(v.y); s.z = f2bf(v.z); s.w = f2bf(v.w);
            *reinterpret_cast<short4*>(&lds[r * LDSW + c4]) = s;
        }
    }

    // ---- B fragments -> 60 VGPRs (independent of LDS; issue before barrier) ----
    const int lane = tid & 63;
    const bf16x8* bt = reinterpret_cast<const bf16x8*>(btab) + lane;
    bf16x8 B[KH];
#pragma unroll
    for (int kh = 0; kh < KH; ++kh)
        B[kh] = bt[kh * 64];          // coalesced dwordx4, 1 KB/wave, L2-hot

    __syncthreads();

    // ---------------- compute: 15 kh x 4 x-tiles of 16x16 MFMA ----------------
    const int wv   = tid >> 6;        // wave id 0..3 -> output rows [16*wv, +16)
    const int m    = lane & 15;       // A-row (and D-col) index
    const int q    = lane >> 4;       // quad

    f32x4 acc[4];
#pragma unroll
    for (int t = 0; t < 4; ++t) acc[t] = (f32x4){0.f, 0.f, 0.f, 0.f};

    // A-frag base: row (16*wv + m), col q*8 + t*16 (imm-friendly offsets)
    const short* abase = &lds[(wv * 16 + m) * LDSW + q * 8];
#pragma unroll
    for (int kh = 0; kh < KH; ++kh) {
#pragma unroll
        for (int t = 0; t < 4; ++t) {
            const bf16x8 a =
                *reinterpret_cast<const bf16x8*>(abase + kh * LDSW + t * 16);  // ds_read_b128
            acc[t] = __builtin_amdgcn_mfma_f32_16x16x32_bf16(a, B[kh], acc[t], 0, 0, 0);
        }
    }

    // ---------------- epilogue: D layout col=lane&15, row=q*4+reg ----------------
    const float b0 = bias[0];
    const int row0 = oy0 + wv * 16 + q * 4;
#pragma unroll
    for (int t = 0; t < 4; ++t) {
        const int col = ox0 + t * 16 + m;
        if (col < OW) {
#pragma unroll
            for (int r = 0; r < 4; ++r) {
                const int row = row0 + r;
                if (row < OH)
                    out[(size_t)row * OW + col] = acc[t][r] + b0;
            }
        }
    }
}

extern "C" void kernel_launch(void* const* d_in, const int* in_sizes, int n_in,
                              void* d_out, int out_size, void* d_ws, size_t ws_size,
                              hipStream_t stream) {
    const float* x    = (const float*)d_in[0];
    const float* w    = (const float*)d_in[1];
    const float* bias = (const float*)d_in[2];
    float* out        = (float*)d_out;
    short* btab       = (short*)d_ws;   // 15*64*8 shorts = 15360 B

    conv2d_btab<<<dim3((KH * 64 + 255) / 256), dim3(256), 0, stream>>>(w, btab);

    dim3 grid((OW + BX - 1) / BX, (OH + BY - 1) / BY);  // 64 x 64
    dim3 block(256);
    conv2d_mfma<<<grid, block, 0, stream>>>(x, btab, bias, out);
}